// Round 3
// baseline (59862.292 us; speedup 1.0000x reference)
//
#include <hip/hip_runtime.h>
#include <stdint.h>

#define HH 640
#define BB 128
#define TT 512
#define VV 4097
#define G4 2560   // 4*HH
#define VP 4352   // padded Wout width (17*256)

typedef float f32x8 __attribute__((ext_vector_type(8)));
typedef float f32x2 __attribute__((ext_vector_type(2)));

__device__ __forceinline__ float sigm(float x){ return 1.0f/(1.0f+expf(-x)); }

// monotonic packed key: larger logit wins; ties -> smaller v (jnp.argmax first-index)
__device__ __forceinline__ unsigned long long packkey(float f, unsigned v){
    unsigned u = __float_as_uint(f);
    unsigned m = (u & 0x80000000u) ? ~u : (u | 0x80000000u);
    return ((unsigned long long)m << 32) | (unsigned long long)(~v);
}

// bijective XCD partition
__device__ __forceinline__ int xcd_tile(int bid, int per){ return (bid & 7)*per + (bid >> 3); }

// transposed state addressing: [k>>2][b][k&3] as float index
__device__ __forceinline__ size_t taddr(int k, int b){
    return ((size_t)(k>>2)*BB + b)*4 + (k&3);
}

// ---------------- init (old linear layout) ----------------
__global__ __launch_bounds__(256) void k_init(const float* __restrict__ h0, const float* __restrict__ c0,
                       float* __restrict__ hs0, float* __restrict__ cs,
                       int* __restrict__ label, unsigned long long* __restrict__ slot){
    int i = blockIdx.x*256 + threadIdx.x;
    if (i < BB*HH){ hs0[i] = h0[i]; cs[i] = c0[i]; }
    if (i < BB){ label[i] = 0; slot[i] = 0ULL; }
}
// ---------------- init (new transposed layout) ----------------
__global__ __launch_bounds__(256) void k_init2(const float* __restrict__ h0, const float* __restrict__ c0,
                       float* __restrict__ hs0, float* __restrict__ cs,
                       int* __restrict__ label, unsigned long long* __restrict__ slot){
    int i = blockIdx.x*256 + threadIdx.x;
    if (i < BB*HH){
        int b = i / HH, jj = i % HH;
        size_t o = taddr(jj, b);
        hs0[o] = h0[i]; cs[o] = c0[i];
    }
    if (i < BB){ label[i] = 0; slot[i] = 0ULL; }
}

// ---------------- one-time transposes ----------------
// gate-interleaved: WT[k][jj*4+g] = W[(g*HH+jj)*HH + k]
__global__ __launch_bounds__(256) void k_tr_gate(const float* __restrict__ W, float* __restrict__ WT){
    int idx = blockIdx.x*256 + threadIdx.x;   // 2560*160
    if (idx >= G4*160) return;
    int row = idx / 160, kq = idx % 160;
    int g = row / HH, jj = row % HH;
    float4 f = *reinterpret_cast<const float4*>(W + (size_t)row*HH + kq*4);
    WT[(size_t)(kq*4+0)*G4 + jj*4+g] = f.x;
    WT[(size_t)(kq*4+1)*G4 + jj*4+g] = f.y;
    WT[(size_t)(kq*4+2)*G4 + jj*4+g] = f.z;
    WT[(size_t)(kq*4+3)*G4 + jj*4+g] = f.w;
}
// WT[k][n] = W[n*HH+k], 640x640
__global__ __launch_bounds__(256) void k_tr640(const float* __restrict__ W, float* __restrict__ WT){
    int idx = blockIdx.x*256 + threadIdx.x;   // 640*160
    if (idx >= HH*160) return;
    int n = idx / 160, kq = idx % 160;
    float4 f = *reinterpret_cast<const float4*>(W + (size_t)n*HH + kq*4);
    WT[(size_t)(kq*4+0)*HH + n] = f.x;
    WT[(size_t)(kq*4+1)*HH + n] = f.y;
    WT[(size_t)(kq*4+2)*HH + n] = f.z;
    WT[(size_t)(kq*4+3)*HH + n] = f.w;
}
// WoutT[k][v] padded to VP, zero pad
__global__ __launch_bounds__(256) void k_tr_wout(const float* __restrict__ W, float* __restrict__ WT){
    int idx = blockIdx.x*256 + threadIdx.x;   // VP*160
    if (idx >= VP*160) return;
    int v = idx / 160, kq = idx % 160;
    float4 f = make_float4(0.f,0.f,0.f,0.f);
    if (v < VV) f = *reinterpret_cast<const float4*>(W + (size_t)v*HH + kq*4);
    WT[(size_t)(kq*4+0)*VP + v] = f.x;
    WT[(size_t)(kq*4+1)*VP + v] = f.y;
    WT[(size_t)(kq*4+2)*VP + v] = f.z;
    WT[(size_t)(kq*4+3)*VP + v] = f.w;
}
// padded bias: boutP[v] = v<VV ? b_out[v] : -1e30
__global__ __launch_bounds__(256) void k_boutpad(const float* __restrict__ b_out, float* __restrict__ boutP){
    int v = blockIdx.x*256 + threadIdx.x;
    if (v < VP) boutP[v] = (v < VV) ? b_out[v] : -1e30f;
}

// ---------------- emb_proj precompute: [VV+1][2560] gate-interleaved; row VV = bias-only ----------------
__global__ __launch_bounds__(256) void k_embproj(const float* __restrict__ embedding,
                          const float* __restrict__ Wih,
                          const float* __restrict__ b_ih, const float* __restrict__ b_hh,
                          float* __restrict__ embproj){
    int tile = xcd_tile(blockIdx.x, 322);
    if (tile >= 2570) return;
    int ut = tile / 257;
    int vg = tile % 257;
    int u  = ut*256 + threadIdx.x;
    float acc[16];
    #pragma unroll
    for (int i=0;i<16;i++) acc[i]=0.f;
    const float* wr = Wih + (size_t)u*HH;
    for (int kc=0; kc<HH; kc+=16){
        float wv[16];
        #pragma unroll
        for (int q=0;q<4;q++){
            float4 f = *reinterpret_cast<const float4*>(wr + kc + q*4);
            wv[q*4+0]=f.x; wv[q*4+1]=f.y; wv[q*4+2]=f.z; wv[q*4+3]=f.w;
        }
        #pragma unroll
        for (int vi=0; vi<16; ++vi){
            int v = vg*16+vi;
            if (v < VV){
                const float* ep = embedding + (size_t)v*HH + kc;
                float a = acc[vi];
                #pragma unroll
                for (int k=0;k<16;k++) a = fmaf(ep[k], wv[k], a);
                acc[vi] = a;
            }
        }
    }
    float bias = b_ih[u] + b_hh[u];
    int g = u / HH, jj = u % HH;
    #pragma unroll
    for (int vi=0; vi<16; ++vi){
        int v = vg*16+vi;
        if (v <= VV) embproj[(size_t)v*G4 + jj*4 + g] = acc[vi] + bias;
    }
}

// ---------------- enc_proj precompute (old layout [t][b][n]) ----------------
__global__ __launch_bounds__(128) void k_encproj(const float* __restrict__ x,
                          const float* __restrict__ Wenc, const float* __restrict__ b_enc,
                          float* __restrict__ encproj){
    int tile = xcd_tile(blockIdx.x, 2560);
    int b   = tile / 160;
    int rem = tile % 160;
    int tt  = rem / 5;
    int nt2 = rem % 5;
    int lane = threadIdx.x & 63, w = threadIdx.x >> 6;
    int n = nt2*128 + w*64 + lane;
    float acc[16];
    #pragma unroll
    for (int i=0;i<16;i++) acc[i]=0.f;
    const float* wr = Wenc + (size_t)n*HH;
    for (int kc=0; kc<HH; kc+=16){
        float wv[16];
        #pragma unroll
        for (int q=0;q<4;q++){
            float4 f = *reinterpret_cast<const float4*>(wr + kc + q*4);
            wv[q*4+0]=f.x; wv[q*4+1]=f.y; wv[q*4+2]=f.z; wv[q*4+3]=f.w;
        }
        #pragma unroll
        for (int k=0;k<16;k++){
            const float* xp = x + (size_t)b*HH*TT + (size_t)(kc+k)*TT + tt*16;
            float ww = wv[k];
            #pragma unroll
            for (int ti=0; ti<16; ++ti) acc[ti] = fmaf(xp[ti], ww, acc[ti]);
        }
    }
    float be = b_enc[n];
    #pragma unroll
    for (int ti=0; ti<16; ++ti)
        encproj[(size_t)(tt*16+ti)*BB*HH + (size_t)b*HH + n] = acc[ti] + be;
}
// ---------------- enc_proj precompute (NEW layout [t][n][b]) ----------------
__global__ __launch_bounds__(128) void k_encprojT(const float* __restrict__ x,
                          const float* __restrict__ Wenc, const float* __restrict__ b_enc,
                          float* __restrict__ encprojT){
    int tile = xcd_tile(blockIdx.x, 2560);
    int b   = tile / 160;
    int rem = tile % 160;
    int tt  = rem / 5;
    int nt2 = rem % 5;
    int lane = threadIdx.x & 63, w = threadIdx.x >> 6;
    int n = nt2*128 + w*64 + lane;
    float acc[16];
    #pragma unroll
    for (int i=0;i<16;i++) acc[i]=0.f;
    const float* wr = Wenc + (size_t)n*HH;
    for (int kc=0; kc<HH; kc+=16){
        float wv[16];
        #pragma unroll
        for (int q=0;q<4;q++){
            float4 f = *reinterpret_cast<const float4*>(wr + kc + q*4);
            wv[q*4+0]=f.x; wv[q*4+1]=f.y; wv[q*4+2]=f.z; wv[q*4+3]=f.w;
        }
        #pragma unroll
        for (int k=0;k<16;k++){
            const float* xp = x + (size_t)b*HH*TT + (size_t)(kc+k)*TT + tt*16;
            float ww = wv[k];
            #pragma unroll
            for (int ti=0; ti<16; ++ti) acc[ti] = fmaf(xp[ti], ww, acc[ti]);
        }
    }
    float be = b_enc[n];
    #pragma unroll
    for (int ti=0; ti<16; ++ti)
        encprojT[((size_t)(tt*16+ti)*HH + n)*BB + b] = acc[ti] + be;
}

// ================= NEW lane=batch kernels =================

// ---- P1: gates = h @ WhhT (scalar weights) + embproj[sel]; LSTM nonlin; lazy commit ----
__global__ __launch_bounds__(256) void k2_p1(
    const float* __restrict__ WhhT,      // [640][2560] gate-interleaved
    const float* __restrict__ embproj,   // [VV+1][2560]
    const int* __restrict__ lens,
    const float* __restrict__ hsrT, float* __restrict__ hswT,
    const float* __restrict__ h1rT, float* __restrict__ h1wT,
    float* __restrict__ csT, float* __restrict__ c1T,
    int* __restrict__ label,
    const unsigned long long* __restrict__ slot,
    float* __restrict__ out_emit, int t)
{
    int tile = xcd_tile(blockIdx.x, 20);   // 160 blocks: tile*16 j-units each
    int wp = __builtin_amdgcn_readfirstlane(threadIdx.x >> 7);  // wave-pair 0/1
    int b  = threadIdx.x & 127;
    int u0 = tile*16 + wp*8;               // 8 gate-interleaved units = 2 jj x 4 gates

    bool mask; int kprev = 0, sel;
    if (t == 0){ mask = true; sel = 0; }
    else {
        unsigned long long key = slot[b];
        int k = (int)(~(unsigned)key);
        int lab = label[b];
        mask = ((t-1) >= lens[b]) || (k == 0);
        kprev = k; sel = mask ? lab : k;
    }
    int erow = (t == 0) ? VV : sel;
    const float4* ep = reinterpret_cast<const float4*>(embproj + (size_t)erow*G4 + u0);
    float4 e0 = ep[0], e1 = ep[1];

    const float4* hp = reinterpret_cast<const float4*>(mask ? hsrT : h1rT) + b;
    const float* wb = WhhT + u0;

    float acc[8];
    #pragma unroll
    for (int j=0;j<8;++j) acc[j]=0.f;

    for (int k4=0; k4<160; ++k4){
        float4 hv = hp[(size_t)k4*BB];
        #pragma unroll
        for (int q=0;q<4;++q){
            f32x8 wv = *reinterpret_cast<const f32x8*>(wb + (size_t)(k4*4+q)*G4);
            float h = (q==0)?hv.x:(q==1)?hv.y:(q==2)?hv.z:hv.w;
            #pragma unroll
            for (int j=0;j<8;++j) acc[j] = fmaf(wv[j], h, acc[j]);
        }
    }

    int jj0 = u0 >> 2;
    #pragma unroll
    for (int r=0;r<2;++r){
        float4 e = r ? e1 : e0;
        float gi = acc[4*r+0] + e.x;
        float gf = acc[4*r+1] + e.y;
        float gG = acc[4*r+2] + e.z;
        float go = acc[4*r+3] + e.w;
        int jj = jj0 + r;
        size_t o = taddr(jj, b);
        float ce = mask ? csT[o] : c1T[o];
        float c2 = sigm(gf)*ce + sigm(gi)*tanhf(gG);
        float h2 = sigm(go)*tanhf(c2);
        float he = mask ? hsrT[o] : h1rT[o];
        csT[o] = ce; c1T[o] = c2; hswT[o] = he; h1wT[o] = h2;
    }
    if (tile==0 && wp==0 && t>0){   // threads 0..127, one per b
        out_emit[(size_t)b*TT + (t-1)] = mask ? 0.0f : (float)kprev;
        label[b] = sel;
    }
}

// ---- P2: jointT = relu(h1 @ WpredT + b_pred + encprojT[t]) ; reset slot ----
__global__ __launch_bounds__(256) void k2_p2(
    const float* __restrict__ WpredT,    // [640][640]
    const float* __restrict__ encprojT,  // [T][640][128]
    const float* __restrict__ b_pred,
    const float* __restrict__ h1T,
    float* __restrict__ jointT,
    unsigned long long* __restrict__ slot, int t)
{
    int tile = xcd_tile(blockIdx.x, 20);   // 160 blocks: 4 n each
    int wp = __builtin_amdgcn_readfirstlane(threadIdx.x >> 7);
    int b  = threadIdx.x & 127;
    int n0 = tile*4 + wp*2;

    const float4* hp = reinterpret_cast<const float4*>(h1T) + b;
    const float* wb = WpredT + n0;
    float acc0 = 0.f, acc1 = 0.f;
    for (int k4=0; k4<160; ++k4){
        float4 hv = hp[(size_t)k4*BB];
        #pragma unroll
        for (int q=0;q<4;++q){
            f32x2 wv = *reinterpret_cast<const f32x2*>(wb + (size_t)(k4*4+q)*HH);
            float h = (q==0)?hv.x:(q==1)?hv.y:(q==2)?hv.z:hv.w;
            acc0 = fmaf(wv[0], h, acc0);
            acc1 = fmaf(wv[1], h, acc1);
        }
    }
    float bp0 = b_pred[n0], bp1 = b_pred[n0+1];
    float en0 = encprojT[((size_t)t*HH + n0  )*BB + b];
    float en1 = encprojT[((size_t)t*HH + n0+1)*BB + b];
    size_t o = taddr(n0, b);
    jointT[o]   = fmaxf(acc0 + bp0 + en0, 0.f);
    jointT[o+1] = fmaxf(acc1 + bp1 + en1, 0.f);   // n0&3 in {0,2}: same float4 group
    if (tile==0 && wp==0) slot[b] = 0ULL;
}

// ---- P3: logits + argmax ----
__global__ __launch_bounds__(256) void k2_p3(
    const float* __restrict__ WoutT,  // [640][VP]
    const float* __restrict__ boutP,  // [VP], pad = -1e30
    const float* __restrict__ jointT,
    unsigned long long* __restrict__ slot)
{
    int tile = xcd_tile(blockIdx.x, 34);   // 272 blocks: 16 v each
    int wp = __builtin_amdgcn_readfirstlane(threadIdx.x >> 7);
    int b  = threadIdx.x & 127;
    int v0 = tile*16 + wp*8;

    const float4* jp = reinterpret_cast<const float4*>(jointT) + b;
    const float* wb = WoutT + v0;
    float acc[8];
    #pragma unroll
    for (int j=0;j<8;++j) acc[j]=0.f;

    for (int k4=0; k4<160; ++k4){
        float4 hv = jp[(size_t)k4*BB];
        #pragma unroll
        for (int q=0;q<4;++q){
            f32x8 wv = *reinterpret_cast<const f32x8*>(wb + (size_t)(k4*4+q)*VP);
            float h = (q==0)?hv.x:(q==1)?hv.y:(q==2)?hv.z:hv.w;
            #pragma unroll
            for (int j=0;j<8;++j) acc[j] = fmaf(wv[j], h, acc[j]);
        }
    }
    f32x8 bo = *reinterpret_cast<const f32x8*>(boutP + v0);
    unsigned long long key = 0ULL;
    #pragma unroll
    for (int j=0;j<8;++j){
        unsigned long long kk = packkey(acc[j] + bo[j], (unsigned)(v0+j));
        if (kk > key) key = kk;
    }
    __shared__ unsigned long long red[2][128];
    red[wp][b] = key;
    __syncthreads();
    if (threadIdx.x < 128){
        int bb = threadIdx.x;
        unsigned long long m = red[0][bb];
        if (red[1][bb] > m) m = red[1][bb];
        atomicMax(&slot[bb], m);
    }
}

// ---- final: emit t=511, hF, cF (transposed state) ----
__global__ __launch_bounds__(256) void k_final2(const int* __restrict__ lens,
                        const unsigned long long* __restrict__ slot,
                        const float* __restrict__ hsT, const float* __restrict__ h1T,
                        const float* __restrict__ csT, const float* __restrict__ c1T,
                        float* __restrict__ dout)
{
    int i = blockIdx.x*256 + threadIdx.x;
    if (i >= BB*HH) return;
    int b = i / HH, jj = i % HH;
    size_t o = taddr(jj, b);
    unsigned long long key = slot[b];
    int k = (int)(~(unsigned)key);
    bool m = ((TT-1) >= lens[b]) || (k == 0);
    dout[BB*TT + i]         = m ? hsT[o] : h1T[o];
    dout[BB*TT + BB*HH + i] = m ? csT[o] : c1T[o];
    if (i < BB){
        unsigned long long key2 = slot[i];
        int k2 = (int)(~(unsigned)key2);
        bool mm = ((TT-1) >= lens[i]) || (k2 == 0);
        dout[(size_t)i*TT + (TT-1)] = mm ? 0.0f : (float)k2;
    }
}

// ================= OLD (R2) kernels kept as fallback =================
template<int HAS_EMB>
__global__ __launch_bounds__(256) void k_p1n(
    const float* __restrict__ WhhT,
    const float* __restrict__ WihT,
    const float* __restrict__ embproj,
    const float* __restrict__ embedding,
    const float* __restrict__ b_ih, const float* __restrict__ b_hh,
    const int* __restrict__ lens,
    const float* __restrict__ hs_r, float* __restrict__ hs_w,
    const float* __restrict__ h1_r, float* __restrict__ h1_w,
    float* __restrict__ c_state, float* __restrict__ c1,
    int* __restrict__ label,
    const unsigned long long* __restrict__ slot,
    float* __restrict__ out_emit, int t)
{
    int tile = xcd_tile(blockIdx.x, 20);
    int jt = tile / 16, bg = tile & 15;
    int l = threadIdx.x & 63, w = threadIdx.x >> 6;
    int b0 = bg << 3;
    int jj = jt*64 + l;

    bool mask[8]; int kprev[8]; int sel[8];
    #pragma unroll
    for (int bi=0; bi<8; ++bi){
        int b = b0+bi;
        if (t == 0){ mask[bi]=true; sel[bi]=0; kprev[bi]=0; }
        else {
            unsigned long long key = slot[b];
            int k = (int)(~(unsigned)key);
            int lab = label[b];
            bool m = ((t-1) >= lens[b]) || (k == 0);
            mask[bi]=m; kprev[bi]=k; sel[bi] = m ? lab : k;
        }
    }
    const float* hp[8];
    #pragma unroll
    for (int bi=0; bi<8; ++bi)
        hp[bi] = (mask[bi] ? hs_r : h1_r) + (size_t)(b0+bi)*HH + w*160;

    float acc[4][8];
    #pragma unroll
    for (int g=0; g<4; ++g)
        #pragma unroll
        for (int bi=0; bi<8; ++bi) acc[g][bi]=0.f;

    const float* wb  = WhhT + (size_t)(w*160)*G4 + jj*4;
    const float* wb2 = WihT + (size_t)(w*160)*G4 + jj*4;

    for (int kk=0; kk<160; kk+=4){
        float4 hv[8];
        #pragma unroll
        for (int bi=0; bi<8; ++bi)
            hv[bi] = *reinterpret_cast<const float4*>(hp[bi] + kk);
        #pragma unroll
        for (int q=0; q<4; ++q){
            float4 wv = *reinterpret_cast<const float4*>(wb + (size_t)(kk+q)*G4);
            #pragma unroll
            for (int bi=0; bi<8; ++bi){
                float h = q==0?hv[bi].x: q==1?hv[bi].y: q==2?hv[bi].z: hv[bi].w;
                acc[0][bi]=fmaf(wv.x,h,acc[0][bi]);
                acc[1][bi]=fmaf(wv.y,h,acc[1][bi]);
                acc[2][bi]=fmaf(wv.z,h,acc[2][bi]);
                acc[3][bi]=fmaf(wv.w,h,acc[3][bi]);
            }
        }
        if (!HAS_EMB){
            if (t > 0){
                #pragma unroll
                for (int q=0; q<4; ++q){
                    float4 wv2 = *reinterpret_cast<const float4*>(wb2 + (size_t)(kk+q)*G4);
                    #pragma unroll
                    for (int bi=0; bi<8; ++bi){
                        float e = embedding[(size_t)sel[bi]*HH + w*160 + kk + q];
                        acc[0][bi]=fmaf(wv2.x,e,acc[0][bi]);
                        acc[1][bi]=fmaf(wv2.y,e,acc[1][bi]);
                        acc[2][bi]=fmaf(wv2.z,e,acc[2][bi]);
                        acc[3][bi]=fmaf(wv2.w,e,acc[3][bi]);
                    }
                }
            }
        }
    }
    __shared__ float red[4][32][64];
    #pragma unroll
    for (int g=0; g<4; ++g)
        #pragma unroll
        for (int bi=0; bi<8; ++bi)
            red[w][g*8+bi][l] = acc[g][bi];
    __syncthreads();

    float bsum[4];
    if (!HAS_EMB){
        #pragma unroll
        for (int g=0; g<4; ++g) bsum[g] = b_ih[g*HH+jj] + b_hh[g*HH+jj];
    }
    #pragma unroll
    for (int r=0; r<2; ++r){
        int bi = w*2 + r;
        float gg4[4];
        #pragma unroll
        for (int g=0; g<4; ++g)
            gg4[g] = red[0][g*8+bi][l]+red[1][g*8+bi][l]+red[2][g*8+bi][l]+red[3][g*8+bi][l];
        if (HAS_EMB){
            int row = (t==0) ? VV : sel[bi];
            float4 e = *reinterpret_cast<const float4*>(embproj + (size_t)row*G4 + jj*4);
            gg4[0]+=e.x; gg4[1]+=e.y; gg4[2]+=e.z; gg4[3]+=e.w;
        } else {
            #pragma unroll
            for (int g=0; g<4; ++g) gg4[g]+=bsum[g];
        }
        size_t o = (size_t)(b0+bi)*HH + jj;
        float ce = mask[bi] ? c_state[o] : c1[o];
        float c2v = sigm(gg4[1])*ce + sigm(gg4[0])*tanhf(gg4[2]);
        float h2 = sigm(gg4[3])*tanhf(c2v);
        float he = mask[bi] ? hs_r[o] : h1_r[o];
        c_state[o]=ce; c1[o]=c2v; hs_w[o]=he; h1_w[o]=h2;
    }
    if (jt==0 && t>0 && threadIdx.x<8){
        int bi=threadIdx.x; int b=b0+bi;
        out_emit[(size_t)b*TT + (t-1)] = mask[bi]?0.0f:(float)kprev[bi];
        label[b] = sel[bi];
    }
}

template<int HAS_ENC>
__global__ __launch_bounds__(256) void k_p2n(
    const float* __restrict__ WpredT,
    const float* __restrict__ WencT,
    const float* __restrict__ x,
    const float* __restrict__ encproj,
    const float* __restrict__ b_enc,
    const float* __restrict__ b_pred,
    const float* __restrict__ h1,
    float* __restrict__ joint,
    unsigned long long* __restrict__ slot,
    int t)
{
    int tile = xcd_tile(blockIdx.x, 20);
    int nt = tile / 32, bg = tile % 32;
    int l = threadIdx.x & 63, w = threadIdx.x >> 6;
    int b0 = bg*4;
    int n0 = nt*128 + l*2;
    float acc[2][4];
    #pragma unroll
    for (int ni=0;ni<2;++ni)
        #pragma unroll
        for (int bi=0;bi<4;++bi) acc[ni][bi]=0.f;
    const float* wb = WpredT + (size_t)(w*160)*HH + n0;
    const float* eb = WencT  + (size_t)(w*160)*HH + n0;
    const float* hb[4];
    #pragma unroll
    for (int bi=0; bi<4; ++bi) hb[bi] = h1 + (size_t)(b0+bi)*HH + w*160;

    for (int kk=0; kk<160; kk+=4){
        float4 hv[4];
        #pragma unroll
        for (int bi=0; bi<4; ++bi) hv[bi] = *reinterpret_cast<const float4*>(hb[bi]+kk);
        float xv[4][4];
        if (!HAS_ENC){
            #pragma unroll
            for (int bi=0; bi<4; ++bi)
                #pragma unroll
                for (int q=0; q<4; ++q)
                    xv[bi][q] = x[(size_t)(b0+bi)*HH*TT + (size_t)(w*160+kk+q)*TT + t];
        }
        #pragma unroll
        for (int q=0; q<4; ++q){
            float2 wv = *reinterpret_cast<const float2*>(wb + (size_t)(kk+q)*HH);
            float2 ev = make_float2(0.f,0.f);
            if (!HAS_ENC) ev = *reinterpret_cast<const float2*>(eb + (size_t)(kk+q)*HH);
            #pragma unroll
            for (int bi=0; bi<4; ++bi){
                float h = q==0?hv[bi].x:q==1?hv[bi].y:q==2?hv[bi].z:hv[bi].w;
                acc[0][bi]=fmaf(wv.x,h,acc[0][bi]);
                acc[1][bi]=fmaf(wv.y,h,acc[1][bi]);
                if (!HAS_ENC){
                    acc[0][bi]=fmaf(ev.x,xv[bi][q],acc[0][bi]);
                    acc[1][bi]=fmaf(ev.y,xv[bi][q],acc[1][bi]);
                }
            }
        }
    }
    __shared__ float red2[4][8][64];
    #pragma unroll
    for (int ni=0; ni<2; ++ni)
        #pragma unroll
        for (int bi=0; bi<4; ++bi)
            red2[w][bi*2+ni][l] = acc[ni][bi];
    __syncthreads();
    #pragma unroll
    for (int pp=0; pp<2; ++pp){
        int p = threadIdx.x + pp*256;
        int b = p >> 7, nidx = p & 127;
        int n = nt*128 + nidx;
        int c = b*2 + (nidx&1), r = nidx>>1;
        float s = red2[0][c][r]+red2[1][c][r]+red2[2][c][r]+red2[3][c][r];
        s += b_pred[n];
        if (HAS_ENC) s += encproj[(size_t)t*BB*HH + (size_t)(b0+b)*HH + n];
        else         s += b_enc[n];
        joint[(size_t)(b0+b)*HH + n] = fmaxf(s, 0.f);
    }
    if (tile==0 && threadIdx.x<BB) slot[threadIdx.x]=0ULL;
}

__global__ __launch_bounds__(256) void k_p3n(
    const float* __restrict__ WoutT,
    const float* __restrict__ b_out,
    const float* __restrict__ joint,
    unsigned long long* __restrict__ slot)
{
    int tile = xcd_tile(blockIdx.x, 34);
    int vt = tile / 16, bg = tile & 15;
    int l = threadIdx.x & 63, w = threadIdx.x >> 6;
    int b0 = bg << 3;
    int v0 = vt*256 + l*4;
    float acc[4][8];
    #pragma unroll
    for (int vi=0;vi<4;++vi)
        #pragma unroll
        for (int bi=0;bi<8;++bi) acc[vi][bi]=0.f;
    const float* wb = WoutT + (size_t)(w*160)*VP + v0;
    const float* jb[8];
    #pragma unroll
    for (int bi=0;bi<8;++bi) jb[bi] = joint + (size_t)(b0+bi)*HH + w*160;
    for (int kk=0; kk<160; kk+=4){
        float4 hv[8];
        #pragma unroll
        for (int bi=0;bi<8;++bi) hv[bi] = *reinterpret_cast<const float4*>(jb[bi]+kk);
        #pragma unroll
        for (int q=0;q<4;++q){
            float4 wv = *reinterpret_cast<const float4*>(wb + (size_t)(kk+q)*VP);
            #pragma unroll
            for (int bi=0;bi<8;++bi){
                float h = q==0?hv[bi].x:q==1?hv[bi].y:q==2?hv[bi].z:hv[bi].w;
                acc[0][bi]=fmaf(wv.x,h,acc[0][bi]);
                acc[1][bi]=fmaf(wv.y,h,acc[1][bi]);
                acc[2][bi]=fmaf(wv.z,h,acc[2][bi]);
                acc[3][bi]=fmaf(wv.w,h,acc[3][bi]);
            }
        }
    }
    __shared__ float red[4][32][64];
    #pragma unroll
    for (int vi=0;vi<4;++vi)
        #pragma unroll
        for (int bi=0;bi<8;++bi)
            red[w][bi*4+vi][l] = acc[vi][bi];
    __syncthreads();
    #pragma unroll
    for (int r=0;r<2;++r){
        int bi = w*2+r;
        unsigned long long key = 0ULL;
        #pragma unroll
        for (int vi=0;vi<4;++vi){
            float s = red[0][bi*4+vi][l]+red[1][bi*4+vi][l]+red[2][bi*4+vi][l]+red[3][bi*4+vi][l];
            int v = vt*256 + l*4 + vi;
            if (v < VV){
                unsigned long long kk2 = packkey(s + b_out[v], (unsigned)v);
                if (kk2 > key) key = kk2;
            }
        }
        #pragma unroll
        for (int off=32; off>0; off>>=1){
            unsigned long long o = __shfl_xor(key, off, 64);
            if (o > key) key = o;
        }
        if (l==0) atomicMax(&slot[b0+bi], key);
    }
}

__global__ __launch_bounds__(256) void k_final(const int* __restrict__ lens,
                        const unsigned long long* __restrict__ slot,
                        const float* __restrict__ hs_r, const float* __restrict__ h1_r,
                        const float* __restrict__ cs,  const float* __restrict__ c1,
                        float* __restrict__ dout)
{
    int i = blockIdx.x*256 + threadIdx.x;
    if (i >= BB*HH) return;
    int b = i / HH;
    unsigned long long key = slot[b];
    int k = (int)(~(unsigned)key);
    bool m = ((TT-1) >= lens[b]) || (k == 0);
    dout[BB*TT + i]         = m ? hs_r[i] : h1_r[i];
    dout[BB*TT + BB*HH + i] = m ? cs[i]   : c1[i];
    if (i < BB){
        unsigned long long key2 = slot[i];
        int k2 = (int)(~(unsigned)key2);
        bool mm = ((TT-1) >= lens[i]) || (k2 == 0);
        dout[(size_t)i*TT + (TT-1)] = mm ? 0.0f : (float)k2;
    }
}

extern "C" void kernel_launch(void* const* d_in, const int* in_sizes, int n_in,
                              void* d_out, int out_size, void* d_ws, size_t ws_size,
                              hipStream_t stream)
{
    const float* x     = (const float*)d_in[0];
    const int*   lens  = (const int*)  d_in[1];
    const float* emb   = (const float*)d_in[2];
    const float* Wih   = (const float*)d_in[3];
    const float* Whh   = (const float*)d_in[4];
    const float* bih   = (const float*)d_in[5];
    const float* bhh   = (const float*)d_in[6];
    const float* Wenc  = (const float*)d_in[7];
    const float* benc  = (const float*)d_in[8];
    const float* Wpred = (const float*)d_in[9];
    const float* bpred = (const float*)d_in[10];
    const float* Wout  = (const float*)d_in[11];
    const float* bout  = (const float*)d_in[12];
    const float* h0    = (const float*)d_in[13];
    const float* c0    = (const float*)d_in[14];
    float* out = (float*)d_out;
    (void)in_sizes; (void)n_in; (void)out_size;

    char* ws = (char*)d_ws;
    size_t off = 0;
    auto alloc = [&](size_t bytes) -> void* {
        void* p = ws + off; off += (bytes + 255) & ~(size_t)255; return p;
    };
    const size_t BH = (size_t)BB*HH*sizeof(float);
    float* hs0  = (float*)alloc(BH);
    float* hs1  = (float*)alloc(BH);
    float* h1b0 = (float*)alloc(BH);
    float* h1b1 = (float*)alloc(BH);
    float* cs   = (float*)alloc(BH);
    float* c1   = (float*)alloc(BH);
    float* joint= (float*)alloc(BH);
    int* label  = (int*)alloc(BB*sizeof(int));
    unsigned long long* slot = (unsigned long long*)alloc(BB*sizeof(unsigned long long));

    float *WhhT=nullptr,*WihT=nullptr,*WpredT=nullptr,*WencT=nullptr,*WoutT=nullptr,*boutP=nullptr;
    bool hasTr=false;
    {
        size_t trBytes = ((size_t)HH*G4*2 + (size_t)HH*HH*2 + (size_t)HH*VP + VP)*sizeof(float) + 6*256;
        if (ws_size >= off + trBytes){
            WhhT  = (float*)alloc((size_t)HH*G4*sizeof(float));
            WihT  = (float*)alloc((size_t)HH*G4*sizeof(float));
            WpredT= (float*)alloc((size_t)HH*HH*sizeof(float));
            WencT = (float*)alloc((size_t)HH*HH*sizeof(float));
            WoutT = (float*)alloc((size_t)HH*VP*sizeof(float));
            boutP = (float*)alloc((size_t)VP*sizeof(float));
            hasTr = true;
        }
    }
    float* embproj = nullptr; float* encproj = nullptr;
    bool hasEmb = false, hasEnc = false;
    size_t embBytes = (size_t)(VV+1)*G4*sizeof(float);
    size_t encBytes = (size_t)TT*BB*HH*sizeof(float);
    if (hasTr && ws_size >= off + embBytes + 256){ embproj = (float*)alloc(embBytes); hasEmb = true; }
    if (hasEmb && ws_size >= off + encBytes + 256){ encproj = (float*)alloc(encBytes); hasEnc = true; }
    bool hasNew = hasEnc;   // new path needs all tiers

    float* hsbuf[2] = {hs0, hs1};
    float* h1buf[2] = {h1b0, h1b1};

    if (hasNew){
        k_init2<<<(BB*HH+255)/256, 256, 0, stream>>>(h0, c0, hs0, cs, label, slot);
        k_tr_gate<<<(G4*160+255)/256, 256, 0, stream>>>(Whh, WhhT);
        k_tr640 <<<(HH*160+255)/256, 256, 0, stream>>>(Wpred, WpredT);
        k_tr_wout<<<(VP*160+255)/256, 256, 0, stream>>>(Wout, WoutT);
        k_boutpad<<<(VP+255)/256, 256, 0, stream>>>(bout, boutP);
        k_embproj<<<2576, 256, 0, stream>>>(emb, Wih, bih, bhh, embproj);
        k_encprojT<<<20480, 128, 0, stream>>>(x, Wenc, benc, encproj);

        for (int t = 0; t < TT; ++t){
            const float* hsr = hsbuf[t & 1];
            float*       hsw = hsbuf[(t+1) & 1];
            const float* h1r = h1buf[(t+1) & 1];
            float*       h1w = h1buf[t & 1];
            k2_p1<<<160, 256, 0, stream>>>(WhhT, embproj, lens, hsr, hsw, h1r, h1w,
                                           cs, c1, label, slot, out, t);
            k2_p2<<<160, 256, 0, stream>>>(WpredT, encproj, bpred, h1w, joint, slot, t);
            k2_p3<<<272, 256, 0, stream>>>(WoutT, boutP, joint, slot);
        }
        k_final2<<<(BB*HH+255)/256, 256, 0, stream>>>(lens, slot, hsbuf[0], h1buf[1], cs, c1, out);
        return;
    }

    // -------- fallback: R2 path --------
    k_init<<<(BB*HH+255)/256, 256, 0, stream>>>(h0, c0, hs0, cs, label, slot);
    if (hasTr){
        k_tr_gate<<<(G4*160+255)/256, 256, 0, stream>>>(Whh, WhhT);
        k_tr_gate<<<(G4*160+255)/256, 256, 0, stream>>>(Wih, WihT);
        k_tr640 <<<(HH*160+255)/256, 256, 0, stream>>>(Wpred, WpredT);
        k_tr640 <<<(HH*160+255)/256, 256, 0, stream>>>(Wenc,  WencT);
        k_tr_wout<<<(VP*160+255)/256, 256, 0, stream>>>(Wout, WoutT);
    }
    if (hasEmb) k_embproj<<<2576, 256, 0, stream>>>(emb, Wih, bih, bhh, embproj);

    for (int t = 0; t < TT; ++t){
        const float* hsr = hsbuf[t & 1];
        float*       hsw = hsbuf[(t+1) & 1];
        const float* h1r = h1buf[(t+1) & 1];
        float*       h1w = h1buf[t & 1];
        if (hasTr){
            if (hasEmb)
                k_p1n<1><<<160, 256, 0, stream>>>(WhhT, WihT, embproj, emb, bih, bhh, lens,
                                                  hsr, hsw, h1r, h1w, cs, c1, label, slot, out, t);
            else
                k_p1n<0><<<160, 256, 0, stream>>>(WhhT, WihT, embproj, emb, bih, bhh, lens,
                                                  hsr, hsw, h1r, h1w, cs, c1, label, slot, out, t);
            k_p2n<0><<<160, 256, 0, stream>>>(WpredT, WencT, x, encproj, benc, bpred, h1w, joint, slot, t);
            k_p3n<<<272, 256, 0, stream>>>(WoutT, bout, joint, slot);
        }
    }
    k_final<<<(BB*HH+255)/256, 256, 0, stream>>>(lens, slot, hsbuf[0], h1buf[1], cs, c1, out);
}